// Round 4
// baseline (161.107 us; speedup 1.0000x reference)
//
#include <hip/hip_runtime.h>

// TreeModel fused kernel, v3b (fix: native vector type for nontemporal loads).
// Tree: complete binary heap, 15 levels (0..14), nodes 0..32766, leaves = nodes 16383..32766.
// out[0..16383] = dot(x[leaf], sum of deltas rows on root->leaf path)
// out[16384]    = sq[0] + sum_{n>=1} sq[n] / max(heights[n]-heights[parent(n)], 1e-7)
//
// Layout: block = 256 threads = 4 waves = 4 consecutive leaves (1 leaf/wave).
// Levels 0..12 are common to the block's 4 leaves -> summed once into LDS.
// Per-leaf residue: levels 13,14 + x row (6 vec4-pair loads, all independent).
// sq ownership (exactly-once, wave-uniform): wave1 -> upper node b (levels 0..11);
// wave2 -> level-12 node 4095+b; even leaves -> their n13; every leaf -> its n14.

constexpr int   N_LEAVES = 16384;
constexpr int   DIM      = 512;
constexpr float MIN_DIST = 1e-7f;

typedef float v4f __attribute__((ext_vector_type(4)));
typedef float v2f __attribute__((ext_vector_type(2)));

__device__ __forceinline__ float v4dot(v4f a, v4f b) {
    return a.x * b.x + a.y * b.y + a.z * b.z + a.w * b.w;
}
__device__ __forceinline__ float v4sq(v4f a) { return v4dot(a, a); }
__device__ __forceinline__ v4f ntload(const v4f* p) {
    return __builtin_nontemporal_load(p);
}

__global__ void zero_scalar_kernel(float* __restrict__ out) {
    if (threadIdx.x == 0) out[N_LEAVES] = 0.0f;
}

__global__ __launch_bounds__(256) void fused_kernel(
        const float* __restrict__ x,
        const float* __restrict__ deltas,
        const float* __restrict__ heights,
        float* __restrict__ out) {
    __shared__ __align__(16) float wtop[DIM];   // sum of levels 0..12 for this leaf group
    __shared__ float sqred[4];

    const int tid  = threadIdx.x;
    const int lane = tid & 63;
    const int wave = tid >> 6;
    const int b    = blockIdx.x;                // leaf group: leaves 4b .. 4b+3

    float sq_acc = 0.0f;   // per-lane partial of delta_total (pre-scaled by 1/branch)

    // ---- Per-leaf independent loads first (maximize loads in flight before barrier).
    const int leaf = 4 * b + wave;
    const int n14  = (N_LEAVES - 1) + leaf;
    const int n13  = (n14 - 1) >> 1;
    const int n12  = (n13 - 1) >> 1;

    const v4f* r14 = (const v4f*)(deltas + (size_t)n14 * DIM);
    const v4f* r13 = (const v4f*)(deltas + (size_t)n13 * DIM);
    const v4f* xr  = (const v4f*)(x      + (size_t)leaf * DIM);

    v4f a14 = ntload(r14 + lane), c14 = ntload(r14 + lane + 64);   // no reuse -> nt
    v4f a13 = r13[lane],          c13 = r13[lane + 64];            // reused by 2 waves
    v4f xa  = ntload(xr + lane),  xc  = ntload(xr + lane + 64);    // no reuse -> nt

    // ---- Stage 1: shared ancestor sum (levels 0..12) into LDS.
    // Thread t accumulates elements [2t, 2t+1]; all 13 loads independent.
    {
        v2f acc = {0.0f, 0.0f};
        #pragma unroll
        for (int l = 0; l <= 12; ++l) {
            const int node = ((1 << l) - 1) + (b >> (12 - l));
            const v2f* row = (const v2f*)(deltas + (size_t)node * DIM);
            v2f v = row[tid];
            acc += v;
        }
        wtop[2 * tid]     = acc.x;
        wtop[2 * tid + 1] = acc.y;
    }

    // ---- sq ownership for upper levels (wave-uniform, overlaps with stage-1 latency).
    if (wave == 1 && b < 4095) {                 // levels 0..11: node b
        const int n = b;
        const v4f* row = (const v4f*)(deltas + (size_t)n * DIM);
        v4f a = row[lane];
        v4f c = row[lane + 64];
        float scale = 1.0f;
        if (n > 0) {
            float br = heights[n] - heights[(n - 1) >> 1];
            scale = 1.0f / fmaxf(br, MIN_DIST);
        }
        sq_acc += (v4sq(a) + v4sq(c)) * scale;
    }
    if (wave == 2) {                             // level 12: node 4095 + b
        const int n = 4095 + b;
        const v4f* row = (const v4f*)(deltas + (size_t)n * DIM);
        v4f a = row[lane];                       // just read by stage 1 -> cache hit
        v4f c = row[lane + 64];
        float br = heights[n] - heights[(n - 1) >> 1];
        sq_acc += (v4sq(a) + v4sq(c)) / fmaxf(br, MIN_DIST);
    }

    // ---- Per-leaf sq contributions (rows already in registers).
    {
        float br = heights[n14] - heights[n13];
        sq_acc += (v4sq(a14) + v4sq(c14)) / fmaxf(br, MIN_DIST);
    }
    if ((leaf & 1) == 0) {                       // even leaf owns its n13
        float br = heights[n13] - heights[n12];
        sq_acc += (v4sq(a13) + v4sq(c13)) / fmaxf(br, MIN_DIST);
    }

    __syncthreads();

    // ---- Dot product: w = wtop + row13 + row14, dot with x, wave-reduce.
    const v4f t0 = ((const v4f*)wtop)[lane];
    const v4f t1 = ((const v4f*)wtop)[lane + 64];
    v4f w0 = t0 + a13 + a14;
    v4f w1 = t1 + c13 + c14;
    float dot = v4dot(xa, w0) + v4dot(xc, w1);
    #pragma unroll
    for (int off = 32; off; off >>= 1) dot += __shfl_xor(dot, off, 64);
    if (lane == 0) out[leaf] = dot;

    // ---- Block-reduce sq_acc, one atomic per block (4096 total).
    #pragma unroll
    for (int off = 32; off; off >>= 1) sq_acc += __shfl_xor(sq_acc, off, 64);
    if (lane == 0) sqred[wave] = sq_acc;
    __syncthreads();
    if (tid == 0)
        atomicAdd(out + N_LEAVES, sqred[0] + sqred[1] + sqred[2] + sqred[3]);
}

extern "C" void kernel_launch(void* const* d_in, const int* in_sizes, int n_in,
                              void* d_out, int out_size, void* d_ws, size_t ws_size,
                              hipStream_t stream) {
    const float* x       = (const float*)d_in[0];
    const float* deltas  = (const float*)d_in[1];
    const float* heights = (const float*)d_in[2];
    float* out = (float*)d_out;

    zero_scalar_kernel<<<1, 64, 0, stream>>>(out);
    fused_kernel<<<N_LEAVES / 4, 256, 0, stream>>>(x, deltas, heights, out);
}

// Round 5
// 119.299 us; speedup vs baseline: 1.3504x; 1.3504x over previous
//
#include <hip/hip_runtime.h>

// TreeModel fused kernel, v4.
// Tree: complete binary heap, 15 levels (0..14), nodes 0..32766, leaves = nodes 16383..32766.
// out[0..16383] = dot(x[leaf], sum of deltas rows on root->leaf path)
// out[16384]    = sq[0] + sum_{n>=1} sq[n] / max(heights[n]-heights[parent(n)], 1e-7)
//
// v4 changes vs v3: no nontemporal loads; no same-address atomics (block partials
// -> d_ws, tiny reduce kernel); 8 leaves/block (2 per wave, leaf pair shares n13,
// wave pair shares n12 which is already loaded for the w-sum).

constexpr int   N_LEAVES = 16384;
constexpr int   DIM      = 512;
constexpr float MIN_DIST = 1e-7f;
constexpr int   LPB      = 8;                   // leaves per block
constexpr int   GRID     = N_LEAVES / LPB;      // 2048

typedef float v4f __attribute__((ext_vector_type(4)));
typedef float v2f __attribute__((ext_vector_type(2)));

__device__ __forceinline__ float v4dot(v4f a, v4f b) {
    return a.x * b.x + a.y * b.y + a.z * b.z + a.w * b.w;
}
__device__ __forceinline__ float v4sq(v4f a) { return v4dot(a, a); }

__global__ __launch_bounds__(256) void fused_kernel(
        const float* __restrict__ x,
        const float* __restrict__ deltas,
        const float* __restrict__ heights,
        float* __restrict__ out,
        float* __restrict__ partial) {
    __shared__ __align__(16) float wtop[DIM];   // sum of levels 0..11 for this leaf group
    __shared__ float sqred[4];

    const int tid  = threadIdx.x;
    const int lane = tid & 63;
    const int wave = tid >> 6;
    const int b    = blockIdx.x;                // leaves 8b .. 8b+7; wave w -> leaves 8b+2w, +1

    // ---- Index math (all wave-uniform).
    const int leaf0 = LPB * b + 2 * wave;            // even leaf of this wave's pair
    const int n14_0 = (N_LEAVES - 1) + leaf0;        // = 16383 + leaf0 (even leaf)
    const int n14_1 = n14_0 + 1;
    const int n13   = (n14_0 - 1) >> 1;              // shared parent of the pair = 8191+4b+w
    const int n12   = (n13 - 1) >> 1;                // = 4095 + 2b + (w>>1)
    const int n11   = (n12 - 1) >> 1;                // = 2047 + b (block-uniform)

    // ---- Issue ALL per-wave row loads up front (12 independent 1 KiB vec4 loads).
    const v4f* r14_0 = (const v4f*)(deltas + (size_t)n14_0 * DIM);
    const v4f* r14_1 = (const v4f*)(deltas + (size_t)n14_1 * DIM);
    const v4f* r13   = (const v4f*)(deltas + (size_t)n13 * DIM);
    const v4f* r12   = (const v4f*)(deltas + (size_t)n12 * DIM);
    const v4f* xr0   = (const v4f*)(x + (size_t)leaf0 * DIM);
    const v4f* xr1   = (const v4f*)(x + (size_t)(leaf0 + 1) * DIM);

    v4f a14_0 = r14_0[lane], c14_0 = r14_0[lane + 64];
    v4f a14_1 = r14_1[lane], c14_1 = r14_1[lane + 64];
    v4f a13   = r13[lane],   c13   = r13[lane + 64];
    v4f a12   = r12[lane],   c12   = r12[lane + 64];
    v4f xa0   = xr0[lane],   xc0   = xr0[lane + 64];
    v4f xa1   = xr1[lane],   xc1   = xr1[lane + 64];

    // ---- Stage 1: shared ancestor sum (levels 0..11) into LDS.
    // Thread t accumulates elements [2t, 2t+1]; all 12 loads independent.
    {
        v2f acc = {0.0f, 0.0f};
        #pragma unroll
        for (int l = 0; l <= 11; ++l) {
            const int node = ((1 << l) - 1) + (b >> (11 - l));
            acc += ((const v2f*)(deltas + (size_t)node * DIM))[tid];
        }
        wtop[2 * tid]     = acc.x;
        wtop[2 * tid + 1] = acc.y;
    }

    // ---- delta_total partials (exactly-once ownership, wave-uniform branches).
    float sq_acc = 0.0f;
    if (wave == 0 && b < 2047) {                 // upper nodes 0..2046: block b owns node b
        const v4f* row = (const v4f*)(deltas + (size_t)b * DIM);
        v4f a = row[lane], c = row[lane + 64];
        float scale = 1.0f;                      // node 0: raw sq
        if (b > 0) scale = 1.0f / fmaxf(heights[b] - heights[(b - 1) >> 1], MIN_DIST);
        sq_acc += (v4sq(a) + v4sq(c)) * scale;
    }
    if (wave == 1) {                             // level-11 node 2047+b (2048 nodes exactly)
        const int n = 2047 + b;
        const v4f* row = (const v4f*)(deltas + (size_t)n * DIM);
        v4f a = row[lane], c = row[lane + 64];
        sq_acc += (v4sq(a) + v4sq(c)) / fmaxf(heights[n] - heights[(n - 1) >> 1], MIN_DIST);
    }
    if ((wave & 1) == 0) {                       // level-12: waves 0,2 own their n12 (in regs)
        sq_acc += (v4sq(a12) + v4sq(c12)) / fmaxf(heights[n12] - heights[n11], MIN_DIST);
    }
    // level-13: each wave owns its pair's shared n13 (in regs)
    sq_acc += (v4sq(a13) + v4sq(c13)) / fmaxf(heights[n13] - heights[n12], MIN_DIST);
    // level-14: both leaves (in regs)
    sq_acc += (v4sq(a14_0) + v4sq(c14_0)) / fmaxf(heights[n14_0] - heights[n13], MIN_DIST);
    sq_acc += (v4sq(a14_1) + v4sq(c14_1)) / fmaxf(heights[n14_1] - heights[n13], MIN_DIST);

    __syncthreads();

    // ---- Dot products: w = wtop + row12 + row13 + row14, dot with x, wave-reduce.
    const v4f t0 = ((const v4f*)wtop)[lane];
    const v4f t1 = ((const v4f*)wtop)[lane + 64];
    v4f base0 = t0 + a12 + a13;
    v4f base1 = t1 + c12 + c13;
    float d0 = v4dot(xa0, base0 + a14_0) + v4dot(xc0, base1 + c14_0);
    float d1 = v4dot(xa1, base0 + a14_1) + v4dot(xc1, base1 + c14_1);
    #pragma unroll
    for (int off = 32; off; off >>= 1) {
        d0 += __shfl_xor(d0, off, 64);
        d1 += __shfl_xor(d1, off, 64);
    }
    if (lane == 0) { out[leaf0] = d0; out[leaf0 + 1] = d1; }

    // ---- Block-reduce sq_acc -> one partial per block (NO atomics).
    #pragma unroll
    for (int off = 32; off; off >>= 1) sq_acc += __shfl_xor(sq_acc, off, 64);
    if (lane == 0) sqred[wave] = sq_acc;
    __syncthreads();
    if (tid == 0) partial[b] = sqred[0] + sqred[1] + sqred[2] + sqred[3];
}

// Single block: reduce 2048 block partials -> out[16384].
__global__ __launch_bounds__(256) void reduce_kernel(
        const float* __restrict__ partial,
        float* __restrict__ out) {
    const int tid = threadIdx.x, lane = tid & 63, wave = tid >> 6;
    const v4f* p = (const v4f*)partial;          // 2048 floats = 512 v4f
    v4f s0 = p[tid];
    v4f s1 = p[tid + 256];
    float s = (s0.x + s0.y + s0.z + s0.w) + (s1.x + s1.y + s1.z + s1.w);
    #pragma unroll
    for (int off = 32; off; off >>= 1) s += __shfl_xor(s, off, 64);
    __shared__ float red[4];
    if (lane == 0) red[wave] = s;
    __syncthreads();
    if (tid == 0) out[N_LEAVES] = red[0] + red[1] + red[2] + red[3];
}

extern "C" void kernel_launch(void* const* d_in, const int* in_sizes, int n_in,
                              void* d_out, int out_size, void* d_ws, size_t ws_size,
                              hipStream_t stream) {
    const float* x       = (const float*)d_in[0];
    const float* deltas  = (const float*)d_in[1];
    const float* heights = (const float*)d_in[2];
    float* out     = (float*)d_out;
    float* partial = (float*)d_ws;               // 2048 floats of scratch

    fused_kernel<<<GRID, 256, 0, stream>>>(x, deltas, heights, out, partial);
    reduce_kernel<<<1, 256, 0, stream>>>(partial, out);
}